// Round 6
// baseline (1572.176 us; speedup 1.0000x reference)
//
#include <hip/hip_runtime.h>
#include <math.h>

#define BB 48
#define TT 32
#define DD 1024
#define SZ 512
#define NCELLS 528  // 32*33/2

typedef unsigned short u16;
typedef unsigned int u32;
typedef __attribute__((ext_vector_type(8))) short bf16x8;
typedef __attribute__((ext_vector_type(4))) float f32x4;

__device__ __forceinline__ int off_of(int k) { return TT * k - (k * (k - 1)) / 2; }

__device__ __forceinline__ u16 f2bf(float x) {
    u32 u = __float_as_uint(x);
    u32 r = (u + 0x7fffu + ((u >> 16) & 1u)) >> 16;
    return (u16)r;
}
__device__ __forceinline__ float bf2f(u16 h) {
    return __uint_as_float(((u32)h) << 16);
}
__device__ __forceinline__ u32 pack2(u16 a, u16 b) {
    return (u32)a | ((u32)b << 16);
}

// ---------------------------------------------------------------------------
// prep_w: Wcat[k][n] (512 x 1536) = [Wtop | Wbot | S] -> WT[n][k] bf16 hi/lo
// ---------------------------------------------------------------------------
__global__ __launch_bounds__(256) void prep_w(
    const float* __restrict__ w_comp, const float* __restrict__ s_bil,
    u16* __restrict__ WT_hi, u16* __restrict__ WT_lo)
{
    int idx = blockIdx.x * 256 + threadIdx.x;   // n*512 + k
    int n = idx >> 9, k = idx & 511;
    float w;
    if (n < 512)       w = w_comp[(size_t)k * SZ + n];
    else if (n < 1024) w = w_comp[(size_t)(512 + k) * SZ + (n - 512)];
    else               w = s_bil[(size_t)k * SZ + (n - 1024)];
    u16 hi = f2bf(w);
    u16 lo = f2bf(w - bf2f(hi));
    WT_hi[idx] = hi;
    WT_lo[idx] = lo;
}

// prep_wl: w_leaf[k][n] (1024 x 512) -> WLT[n][k] bf16 hi/lo
__global__ __launch_bounds__(256) void prep_wl(
    const float* __restrict__ w_leaf,
    u16* __restrict__ WLT_hi, u16* __restrict__ WLT_lo)
{
    int idx = blockIdx.x * 256 + threadIdx.x;   // n*1024 + k
    int n = idx >> 10, k = idx & 1023;
    float w = w_leaf[(size_t)k * SZ + n];
    u16 hi = f2bf(w);
    u16 lo = f2bf(w - bf2f(hi));
    WLT_hi[idx] = hi;
    WLT_lo[idx] = lo;
}

// ---------------------------------------------------------------------------
// leaf_mfma: leaf_pre = relu(x @ w_leaf + b_leaf), split-bf16 MFMA.
// Tile 128x64, 4 waves (2x2), wave 64x32, K=1024, BK=32. grid (8, 12).
// ---------------------------------------------------------------------------
__global__ __launch_bounds__(256) void leaf_mfma(
    const float* __restrict__ x,
    const u16* __restrict__ WLT_hi, const u16* __restrict__ WLT_lo,
    const float* __restrict__ b_leaf, float* __restrict__ leaf_pre)
{
    __shared__ u16 Ah[128][40], Al[128][40];
    __shared__ u16 Bh[64][40],  Bl[64][40];

    const int col0 = blockIdx.x * 64;
    const int row0 = blockIdx.y * 128;
    const int t = threadIdx.x;

    const int srow = t >> 1, skh = (t & 1) * 16;
    const float* ap = x + (size_t)(row0 + srow) * DD + skh;
    const int bcol = t >> 2, bch = (t & 3) * 8;
    const u16* bph = WLT_hi + (size_t)(col0 + bcol) * DD + bch;
    const u16* bpl = WLT_lo + (size_t)(col0 + bcol) * DD + bch;

    const int lane = t & 63, wv = t >> 6;
    const int wr = wv >> 1, wc = wv & 1;
    const int l15 = lane & 15, lko = (lane >> 4) * 8;

    f32x4 acc[4][2];
    #pragma unroll
    for (int i = 0; i < 4; ++i)
        #pragma unroll
        for (int j = 0; j < 2; ++j)
            #pragma unroll
            for (int e = 0; e < 4; ++e) acc[i][j][e] = 0.f;

    float4 pa[4];
    uint4 pbh, pbl;
    #pragma unroll
    for (int c = 0; c < 4; ++c) pa[c] = *(const float4*)(ap + c * 4);
    pbh = *(const uint4*)bph;
    pbl = *(const uint4*)bpl;

    for (int k0 = 0; k0 < DD; k0 += 32) {
        u32 wh[8], wl[8];
        #pragma unroll
        for (int c = 0; c < 4; ++c) {
            float xs[4] = {pa[c].x, pa[c].y, pa[c].z, pa[c].w};
            u16 hh[4], ll[4];
            #pragma unroll
            for (int e = 0; e < 4; ++e) {
                hh[e] = f2bf(xs[e]);
                ll[e] = f2bf(xs[e] - bf2f(hh[e]));
            }
            wh[c * 2]     = pack2(hh[0], hh[1]);
            wh[c * 2 + 1] = pack2(hh[2], hh[3]);
            wl[c * 2]     = pack2(ll[0], ll[1]);
            wl[c * 2 + 1] = pack2(ll[2], ll[3]);
        }
        *(uint4*)&Ah[srow][skh]     = make_uint4(wh[0], wh[1], wh[2], wh[3]);
        *(uint4*)&Ah[srow][skh + 8] = make_uint4(wh[4], wh[5], wh[6], wh[7]);
        *(uint4*)&Al[srow][skh]     = make_uint4(wl[0], wl[1], wl[2], wl[3]);
        *(uint4*)&Al[srow][skh + 8] = make_uint4(wl[4], wl[5], wl[6], wl[7]);
        *(uint4*)&Bh[bcol][bch] = pbh;
        *(uint4*)&Bl[bcol][bch] = pbl;
        __syncthreads();

        if (k0 + 32 < DD) {
            #pragma unroll
            for (int c = 0; c < 4; ++c)
                pa[c] = *(const float4*)(ap + k0 + 32 + c * 4);
            pbh = *(const uint4*)(bph + k0 + 32);
            pbl = *(const uint4*)(bpl + k0 + 32);
        }

        bf16x8 fah[4], fal[4], fbh[2], fbl[2];
        #pragma unroll
        for (int i = 0; i < 4; ++i) {
            fah[i] = *(const bf16x8*)&Ah[wr * 64 + i * 16 + l15][lko];
            fal[i] = *(const bf16x8*)&Al[wr * 64 + i * 16 + l15][lko];
        }
        #pragma unroll
        for (int j = 0; j < 2; ++j) {
            fbh[j] = *(const bf16x8*)&Bh[wc * 32 + j * 16 + l15][lko];
            fbl[j] = *(const bf16x8*)&Bl[wc * 32 + j * 16 + l15][lko];
        }
        #pragma unroll
        for (int i = 0; i < 4; ++i) {
            #pragma unroll
            for (int j = 0; j < 2; ++j) {
                acc[i][j] = __builtin_amdgcn_mfma_f32_16x16x32_bf16(
                    fah[i], fbh[j], acc[i][j], 0, 0, 0);
                acc[i][j] = __builtin_amdgcn_mfma_f32_16x16x32_bf16(
                    fah[i], fbl[j], acc[i][j], 0, 0, 0);
                acc[i][j] = __builtin_amdgcn_mfma_f32_16x16x32_bf16(
                    fal[i], fbh[j], acc[i][j], 0, 0, 0);
            }
        }
        __syncthreads();
    }

    #pragma unroll
    for (int i = 0; i < 4; ++i) {
        int rbase = row0 + wr * 64 + i * 16 + (lane >> 4) * 4;
        #pragma unroll
        for (int j = 0; j < 2; ++j) {
            int gc = col0 + wc * 32 + j * 16 + l15;
            float bc = b_leaf[gc];
            #pragma unroll
            for (int q = 0; q < 4; ++q)
                leaf_pre[(size_t)(rbase + q) * SZ + gc] =
                    fmaxf(acc[i][j][q] + bc, 0.f);
        }
    }
}

// leaf_norm: normalize rows, write chart_h + split Hcur + Sarr=0.
__global__ __launch_bounds__(256) void leaf_norm(
    const float* __restrict__ leaf_pre, float* __restrict__ chart_h,
    u16* __restrict__ Hc_hi, u16* __restrict__ Hc_lo,
    float* __restrict__ Sarr)
{
    const int r = blockIdx.x;               // 0..1535 = b*32+pos
    const int b = r >> 5, pos = r & 31;
    const int t = threadIdx.x, lane = t & 63, wave = t >> 6;
    __shared__ float red[4];

    float2 v = *(const float2*)&leaf_pre[(size_t)r * SZ + 2 * t];
    float sq = v.x * v.x + v.y * v.y;
    #pragma unroll
    for (int o = 32; o; o >>= 1) sq += __shfl_xor(sq, o);
    if (lane == 0) red[wave] = sq;
    __syncthreads();
    float nrm = sqrtf(red[0] + red[1] + red[2] + red[3]);
    float inv = 1.f / fmaxf(nrm, 1e-12f);
    v.x *= inv; v.y *= inv;
    *(float2*)&chart_h[((size_t)b * NCELLS + pos) * SZ + 2 * t] = v;
    u16 hx = f2bf(v.x), hy = f2bf(v.y);
    ((u32*)Hc_hi)[r * 256 + t] = pack2(hx, hy);
    ((u32*)Hc_lo)[r * 256 + t] = pack2(f2bf(v.x - bf2f(hx)), f2bf(v.y - bf2f(hy)));
    if (t == 0) Sarr[(size_t)b * NCELLS + pos] = 0.f;
}

// ---------------------------------------------------------------------------
// transform_mfma: ACU[cell][0:1536] = h[cell] @ Wcat from pre-split Hcur.
// Block 128 rows x 64 cols, 4 waves (2x2), wave 64x32, BK=64 (8 k-steps),
// XCD-swizzled (each XCD owns 3 col-tiles -> W slice 384 KB L2-resident).
// ---------------------------------------------------------------------------
__global__ __launch_bounds__(256) void transform_mfma(
    const u16* __restrict__ Hc_hi, const u16* __restrict__ Hc_lo,
    const u16* __restrict__ WT_hi, const u16* __restrict__ WT_lo,
    float* __restrict__ ACU, int level, int nrow)
{
    __shared__ u16 Ah[128][72], Al[128][72];   // 18432 B each
    __shared__ u16 Bh[64][72],  Bl[64][72];    //  9216 B each
    __shared__ int cidx[128];

    const int L = TT - level, rows = BB * L, off = off_of(level);
    // XCD swizzle: grid = 24*nrow (always % 8 == 0); XCD x gets ct in [3x,3x+3)
    const int cpx = 3 * nrow;
    const int id = blockIdx.x;
    const int w = (id & 7) * cpx + (id >> 3);
    const int ct = w / nrow, rt = w % nrow;
    const int col0 = ct * 64;

    const int t = threadIdx.x;
    if (t < 128) {
        int g = rt * 128 + t;
        cidx[t] = (g < rows) ? ((g / L) * NCELLS + off + (g % L)) : -1;
    }

    const int srow = t >> 1, sk = (t & 1) * 32;
    const u16* aph = Hc_hi + (size_t)(rt * 128 + srow) * SZ + sk;
    const u16* apl = Hc_lo + (size_t)(rt * 128 + srow) * SZ + sk;
    const int bcol = t >> 2, bch = (t & 3) * 16;
    const u16* bph = WT_hi + (size_t)(col0 + bcol) * SZ + bch;
    const u16* bpl = WT_lo + (size_t)(col0 + bcol) * SZ + bch;

    const int lane = t & 63, wv = t >> 6;
    const int wr = wv >> 1, wc = wv & 1;
    const int l15 = lane & 15, lko = (lane >> 4) * 8;

    f32x4 acc[4][2];
    #pragma unroll
    for (int i = 0; i < 4; ++i)
        #pragma unroll
        for (int j = 0; j < 2; ++j)
            #pragma unroll
            for (int e = 0; e < 4; ++e) acc[i][j][e] = 0.f;

    uint4 pah[4], pal[4], pbh[2], pbl[2];
    #pragma unroll
    for (int c = 0; c < 4; ++c) {
        pah[c] = *(const uint4*)(aph + c * 8);
        pal[c] = *(const uint4*)(apl + c * 8);
    }
    #pragma unroll
    for (int c = 0; c < 2; ++c) {
        pbh[c] = *(const uint4*)(bph + c * 8);
        pbl[c] = *(const uint4*)(bpl + c * 8);
    }

    for (int k0 = 0; k0 < SZ; k0 += 64) {
        #pragma unroll
        for (int c = 0; c < 4; ++c) {
            *(uint4*)&Ah[srow][sk + c * 8] = pah[c];
            *(uint4*)&Al[srow][sk + c * 8] = pal[c];
        }
        #pragma unroll
        for (int c = 0; c < 2; ++c) {
            *(uint4*)&Bh[bcol][bch + c * 8] = pbh[c];
            *(uint4*)&Bl[bcol][bch + c * 8] = pbl[c];
        }
        __syncthreads();

        if (k0 + 64 < SZ) {
            #pragma unroll
            for (int c = 0; c < 4; ++c) {
                pah[c] = *(const uint4*)(aph + k0 + 64 + c * 8);
                pal[c] = *(const uint4*)(apl + k0 + 64 + c * 8);
            }
            #pragma unroll
            for (int c = 0; c < 2; ++c) {
                pbh[c] = *(const uint4*)(bph + k0 + 64 + c * 8);
                pbl[c] = *(const uint4*)(bpl + k0 + 64 + c * 8);
            }
        }

        #pragma unroll
        for (int s = 0; s < 2; ++s) {
            bf16x8 fah[4], fal[4], fbh[2], fbl[2];
            #pragma unroll
            for (int i = 0; i < 4; ++i) {
                fah[i] = *(const bf16x8*)&Ah[wr * 64 + i * 16 + l15][s * 32 + lko];
                fal[i] = *(const bf16x8*)&Al[wr * 64 + i * 16 + l15][s * 32 + lko];
            }
            #pragma unroll
            for (int j = 0; j < 2; ++j) {
                fbh[j] = *(const bf16x8*)&Bh[wc * 32 + j * 16 + l15][s * 32 + lko];
                fbl[j] = *(const bf16x8*)&Bl[wc * 32 + j * 16 + l15][s * 32 + lko];
            }
            #pragma unroll
            for (int i = 0; i < 4; ++i) {
                #pragma unroll
                for (int j = 0; j < 2; ++j) {
                    acc[i][j] = __builtin_amdgcn_mfma_f32_16x16x32_bf16(
                        fah[i], fbh[j], acc[i][j], 0, 0, 0);
                    acc[i][j] = __builtin_amdgcn_mfma_f32_16x16x32_bf16(
                        fah[i], fbl[j], acc[i][j], 0, 0, 0);
                    acc[i][j] = __builtin_amdgcn_mfma_f32_16x16x32_bf16(
                        fal[i], fbh[j], acc[i][j], 0, 0, 0);
                }
            }
        }
        __syncthreads();
    }

    #pragma unroll
    for (int i = 0; i < 4; ++i) {
        int rbase = wr * 64 + i * 16 + (lane >> 4) * 4;
        #pragma unroll
        for (int j = 0; j < 2; ++j) {
            int gc = col0 + wc * 32 + j * 16 + l15;
            #pragma unroll
            for (int q = 0; q < 4; ++q) {
                int ci = cidx[rbase + q];
                if (ci >= 0)
                    ACU[(size_t)ci * 1536 + gc] = acc[i][j][q];
            }
        }
    }
}

// ---------------------------------------------------------------------------
// Combine: one block per (b, pos). Writes chart_h + split Hcur + Sarr.
// ---------------------------------------------------------------------------
__global__ __launch_bounds__(256) void combine_kernel(
    float* __restrict__ chart_h, const float* __restrict__ ACU,
    float* __restrict__ Sarr, const float* __restrict__ b_comp,
    u16* __restrict__ Hc_hi, u16* __restrict__ Hc_lo, int level)
{
    const int L = TT - level, N = level;
    const int b = blockIdx.x / L, pos = blockIdx.x % L;
    const int off = off_of(level);

    __shared__ float s_lds[32], p_lds[32];
    __shared__ int lcell[32], rcell[32];
    __shared__ float hred[4][512];
    __shared__ float red[4];

    const int t = threadIdx.x, lane = t & 63, wv = t >> 6;

    if (t < N) {
        lcell[t] = b * NCELLS + off_of(t) + pos;
        rcell[t] = b * NCELLS + off_of(level - t - 1) + pos + t + 1;
    }
    __syncthreads();

    // phase 1: s_n = u_l . h_r + s_l + s_r
    for (int n = wv; n < N; n += 4) {
        const float* u  = ACU + (size_t)lcell[n] * 1536 + 1024;
        const float* hr = chart_h + (size_t)rcell[n] * SZ;
        float d0 = 0.f, d1 = 0.f, d2 = 0.f, d3 = 0.f;
        int j = lane * 2;
        {
            float2 uv = *(const float2*)&u[j];
            float2 hv = *(const float2*)&hr[j];
            d0 = fmaf(uv.x, hv.x, fmaf(uv.y, hv.y, d0));
        }
        {
            float2 uv = *(const float2*)&u[j + 128];
            float2 hv = *(const float2*)&hr[j + 128];
            d1 = fmaf(uv.x, hv.x, fmaf(uv.y, hv.y, d1));
        }
        {
            float2 uv = *(const float2*)&u[j + 256];
            float2 hv = *(const float2*)&hr[j + 256];
            d2 = fmaf(uv.x, hv.x, fmaf(uv.y, hv.y, d2));
        }
        {
            float2 uv = *(const float2*)&u[j + 384];
            float2 hv = *(const float2*)&hr[j + 384];
            d3 = fmaf(uv.x, hv.x, fmaf(uv.y, hv.y, d3));
        }
        float d = (d0 + d1) + (d2 + d3);
        #pragma unroll
        for (int o = 32; o; o >>= 1) d += __shfl_xor(d, o);
        if (lane == 0)
            s_lds[n] = d + Sarr[lcell[n]] + Sarr[rcell[n]];
    }
    __syncthreads();

    // phase 1b: softmax + sbar (wave 0)
    if (wv == 0) {
        float sv = (lane < N) ? s_lds[lane] : -INFINITY;
        float m = sv;
        #pragma unroll
        for (int o = 32; o; o >>= 1) m = fmaxf(m, __shfl_xor(m, o));
        float e = (lane < N) ? expf(sv - m) : 0.f;
        float sum = e;
        #pragma unroll
        for (int o = 32; o; o >>= 1) sum += __shfl_xor(sum, o);
        float p = e / sum;
        if (lane < N) p_lds[lane] = p;
        float sb = (lane < N) ? sv * p : 0.f;
        #pragma unroll
        for (int o = 32; o; o >>= 1) sb += __shfl_xor(sb, o);
        if (lane == 0) Sarr[(size_t)b * NCELLS + off + pos] = sb;
    }
    __syncthreads();

    // phase 2: per-wave partial hbar
    float ax[4], ay[4];
    float2 bc[4];
    #pragma unroll
    for (int q = 0; q < 4; ++q) {
        ax[q] = 0.f; ay[q] = 0.f;
        bc[q] = *(const float2*)&b_comp[lane * 2 + q * 128];
    }
    for (int n = wv; n < N; n += 4) {
        const float* A_ = ACU + (size_t)lcell[n] * 1536;
        const float* C_ = ACU + (size_t)rcell[n] * 1536 + 512;
        float p = p_lds[n];
        #pragma unroll
        for (int q = 0; q < 4; ++q) {
            int j = lane * 2 + q * 128;
            float2 va = *(const float2*)&A_[j];
            float2 vc = *(const float2*)&C_[j];
            ax[q] = fmaf(p, fmaxf(va.x + vc.x + bc[q].x, 0.f), ax[q]);
            ay[q] = fmaf(p, fmaxf(va.y + vc.y + bc[q].y, 0.f), ay[q]);
        }
    }
    #pragma unroll
    for (int q = 0; q < 4; ++q)
        *(float2*)&hred[wv][lane * 2 + q * 128] = make_float2(ax[q], ay[q]);
    __syncthreads();

    float hx = hred[0][2 * t] + hred[1][2 * t] + hred[2][2 * t] + hred[3][2 * t];
    float hy = hred[0][2 * t + 1] + hred[1][2 * t + 1]
             + hred[2][2 * t + 1] + hred[3][2 * t + 1];

    float sq = hx * hx + hy * hy;
    #pragma unroll
    for (int o = 32; o; o >>= 1) sq += __shfl_xor(sq, o);
    if (lane == 0) red[wv] = sq;
    __syncthreads();
    float nrm = sqrtf(red[0] + red[1] + red[2] + red[3]);
    float inv = 1.f / fmaxf(nrm, 1e-12f);
    hx *= inv; hy *= inv;
    size_t obase = ((size_t)b * NCELLS + off + pos) * SZ;
    *(float2*)&chart_h[obase + 2 * t] = make_float2(hx, hy);
    int g = b * L + pos;
    u16 hhx = f2bf(hx), hhy = f2bf(hy);
    ((u32*)Hc_hi)[g * 256 + t] = pack2(hhx, hhy);
    ((u32*)Hc_lo)[g * 256 + t] = pack2(f2bf(hx - bf2f(hhx)), f2bf(hy - bf2f(hhy)));
}

// ---------------------------------------------------------------------------
extern "C" void kernel_launch(void* const* d_in, const int* in_sizes, int n_in,
                              void* d_out, int out_size, void* d_ws, size_t ws_size,
                              hipStream_t stream)
{
    const float* x      = (const float*)d_in[0];
    const float* w_leaf = (const float*)d_in[1];
    const float* b_leaf = (const float*)d_in[2];
    const float* w_comp = (const float*)d_in[3];
    const float* b_comp = (const float*)d_in[4];
    const float* s_bil  = (const float*)d_in[5];
    float* chart_h = (float*)d_out;

    char* ws = (char*)d_ws;
    float* ACU  = (float*)ws;                      ws += (size_t)BB * NCELLS * 1536 * 4;
    float* Sarr = (float*)ws;                      ws += (size_t)BB * NCELLS * 4;
    u16* WT_hi  = (u16*)ws;                        ws += (size_t)1536 * SZ * 2;
    u16* WT_lo  = (u16*)ws;                        ws += (size_t)1536 * SZ * 2;
    u16* WLT_hi = (u16*)ws;                        ws += (size_t)SZ * DD * 2;
    u16* WLT_lo = (u16*)ws;                        ws += (size_t)SZ * DD * 2;
    u16* Hc_hi  = (u16*)ws;                        ws += (size_t)BB * TT * SZ * 2;
    u16* Hc_lo  = (u16*)ws;                        ws += (size_t)BB * TT * SZ * 2;
    float* leaf_pre = (float*)ws;                  ws += (size_t)BB * TT * SZ * 4;

    prep_w<<<(1536 * SZ) / 256, 256, 0, stream>>>(w_comp, s_bil, WT_hi, WT_lo);
    prep_wl<<<(SZ * DD) / 256, 256, 0, stream>>>(w_leaf, WLT_hi, WLT_lo);
    leaf_mfma<<<dim3(8, 12), 256, 0, stream>>>(x, WLT_hi, WLT_lo, b_leaf, leaf_pre);
    leaf_norm<<<BB * TT, 256, 0, stream>>>(leaf_pre, chart_h, Hc_hi, Hc_lo, Sarr);

    {
        int nrow = (BB * TT + 127) / 128;   // 12
        transform_mfma<<<24 * nrow, 256, 0, stream>>>(
            Hc_hi, Hc_lo, WT_hi, WT_lo, ACU, 0, nrow);
    }

    for (int level = 1; level < TT; ++level) {
        int L = TT - level;
        combine_kernel<<<BB * L, 256, 0, stream>>>(
            chart_h, ACU, Sarr, b_comp, Hc_hi, Hc_lo, level);
        if (level < TT - 1) {
            int nrow = (BB * L + 127) / 128;
            transform_mfma<<<24 * nrow, 256, 0, stream>>>(
                Hc_hi, Hc_lo, WT_hi, WT_lo, ACU, level, nrow);
        }
    }
}

// Round 7
// 884.886 us; speedup vs baseline: 1.7767x; 1.7767x over previous
//
#include <hip/hip_runtime.h>
#include <math.h>

#define BB 48
#define TT 32
#define DD 1024
#define SZ 512
#define NCELLS 528  // 32*33/2

typedef unsigned short u16;
typedef unsigned int u32;
typedef __attribute__((ext_vector_type(8))) short bf16x8;
typedef __attribute__((ext_vector_type(4))) float f32x4;

__device__ __forceinline__ int off_of(int k) { return TT * k - (k * (k - 1)) / 2; }

__device__ __forceinline__ u16 f2bf(float x) {
    u32 u = __float_as_uint(x);
    u32 r = (u + 0x7fffu + ((u >> 16) & 1u)) >> 16;
    return (u16)r;
}
__device__ __forceinline__ float bf2f(u16 h) {
    return __uint_as_float(((u32)h) << 16);
}
__device__ __forceinline__ u32 pack2(u16 a, u16 b) {
    return (u32)a | ((u32)b << 16);
}

// ---------------------------------------------------------------------------
// prep_w: Wcat[k][n] (512 x 1536) = [Wtop | Wbot | S] -> WT[n][k] bf16 hi/lo
// ---------------------------------------------------------------------------
__global__ __launch_bounds__(256) void prep_w(
    const float* __restrict__ w_comp, const float* __restrict__ s_bil,
    u16* __restrict__ WT_hi, u16* __restrict__ WT_lo)
{
    int idx = blockIdx.x * 256 + threadIdx.x;   // n*512 + k
    int n = idx >> 9, k = idx & 511;
    float w;
    if (n < 512)       w = w_comp[(size_t)k * SZ + n];
    else if (n < 1024) w = w_comp[(size_t)(512 + k) * SZ + (n - 512)];
    else               w = s_bil[(size_t)k * SZ + (n - 1024)];
    u16 hi = f2bf(w);
    u16 lo = f2bf(w - bf2f(hi));
    WT_hi[idx] = hi;
    WT_lo[idx] = lo;
}

// prep_wl: w_leaf[k][n] (1024 x 512) -> WLT[n][k] bf16 hi/lo
__global__ __launch_bounds__(256) void prep_wl(
    const float* __restrict__ w_leaf,
    u16* __restrict__ WLT_hi, u16* __restrict__ WLT_lo)
{
    int idx = blockIdx.x * 256 + threadIdx.x;   // n*1024 + k
    int n = idx >> 10, k = idx & 1023;
    float w = w_leaf[(size_t)k * SZ + n];
    u16 hi = f2bf(w);
    u16 lo = f2bf(w - bf2f(hi));
    WLT_hi[idx] = hi;
    WLT_lo[idx] = lo;
}

// ---------------------------------------------------------------------------
// leaf_mfma: leaf_pre = relu(x @ w_leaf + b_leaf), split-bf16 MFMA.
// Tile 128x64, 4 waves (2x2), wave 64x32, K=1024, BK=32. grid (8, 12).
// ---------------------------------------------------------------------------
__global__ __launch_bounds__(256) void leaf_mfma(
    const float* __restrict__ x,
    const u16* __restrict__ WLT_hi, const u16* __restrict__ WLT_lo,
    const float* __restrict__ b_leaf, float* __restrict__ leaf_pre)
{
    __shared__ u16 Ah[128][40], Al[128][40];
    __shared__ u16 Bh[64][40],  Bl[64][40];

    const int col0 = blockIdx.x * 64;
    const int row0 = blockIdx.y * 128;
    const int t = threadIdx.x;

    const int srow = t >> 1, skh = (t & 1) * 16;
    const float* ap = x + (size_t)(row0 + srow) * DD + skh;
    const int bcol = t >> 2, bch = (t & 3) * 8;
    const u16* bph = WLT_hi + (size_t)(col0 + bcol) * DD + bch;
    const u16* bpl = WLT_lo + (size_t)(col0 + bcol) * DD + bch;

    const int lane = t & 63, wv = t >> 6;
    const int wr = wv >> 1, wc = wv & 1;
    const int l15 = lane & 15, lko = (lane >> 4) * 8;

    f32x4 acc[4][2];
    #pragma unroll
    for (int i = 0; i < 4; ++i)
        #pragma unroll
        for (int j = 0; j < 2; ++j)
            #pragma unroll
            for (int e = 0; e < 4; ++e) acc[i][j][e] = 0.f;

    float4 pa[4];
    uint4 pbh, pbl;
    #pragma unroll
    for (int c = 0; c < 4; ++c) pa[c] = *(const float4*)(ap + c * 4);
    pbh = *(const uint4*)bph;
    pbl = *(const uint4*)bpl;

    for (int k0 = 0; k0 < DD; k0 += 32) {
        u32 wh[8], wl[8];
        #pragma unroll
        for (int c = 0; c < 4; ++c) {
            float xs[4] = {pa[c].x, pa[c].y, pa[c].z, pa[c].w};
            u16 hh[4], ll[4];
            #pragma unroll
            for (int e = 0; e < 4; ++e) {
                hh[e] = f2bf(xs[e]);
                ll[e] = f2bf(xs[e] - bf2f(hh[e]));
            }
            wh[c * 2]     = pack2(hh[0], hh[1]);
            wh[c * 2 + 1] = pack2(hh[2], hh[3]);
            wl[c * 2]     = pack2(ll[0], ll[1]);
            wl[c * 2 + 1] = pack2(ll[2], ll[3]);
        }
        *(uint4*)&Ah[srow][skh]     = make_uint4(wh[0], wh[1], wh[2], wh[3]);
        *(uint4*)&Ah[srow][skh + 8] = make_uint4(wh[4], wh[5], wh[6], wh[7]);
        *(uint4*)&Al[srow][skh]     = make_uint4(wl[0], wl[1], wl[2], wl[3]);
        *(uint4*)&Al[srow][skh + 8] = make_uint4(wl[4], wl[5], wl[6], wl[7]);
        *(uint4*)&Bh[bcol][bch] = pbh;
        *(uint4*)&Bl[bcol][bch] = pbl;
        __syncthreads();

        if (k0 + 32 < DD) {
            #pragma unroll
            for (int c = 0; c < 4; ++c)
                pa[c] = *(const float4*)(ap + k0 + 32 + c * 4);
            pbh = *(const uint4*)(bph + k0 + 32);
            pbl = *(const uint4*)(bpl + k0 + 32);
        }

        bf16x8 fah[4], fal[4], fbh[2], fbl[2];
        #pragma unroll
        for (int i = 0; i < 4; ++i) {
            fah[i] = *(const bf16x8*)&Ah[wr * 64 + i * 16 + l15][lko];
            fal[i] = *(const bf16x8*)&Al[wr * 64 + i * 16 + l15][lko];
        }
        #pragma unroll
        for (int j = 0; j < 2; ++j) {
            fbh[j] = *(const bf16x8*)&Bh[wc * 32 + j * 16 + l15][lko];
            fbl[j] = *(const bf16x8*)&Bl[wc * 32 + j * 16 + l15][lko];
        }
        #pragma unroll
        for (int i = 0; i < 4; ++i) {
            #pragma unroll
            for (int j = 0; j < 2; ++j) {
                acc[i][j] = __builtin_amdgcn_mfma_f32_16x16x32_bf16(
                    fah[i], fbh[j], acc[i][j], 0, 0, 0);
                acc[i][j] = __builtin_amdgcn_mfma_f32_16x16x32_bf16(
                    fah[i], fbl[j], acc[i][j], 0, 0, 0);
                acc[i][j] = __builtin_amdgcn_mfma_f32_16x16x32_bf16(
                    fal[i], fbh[j], acc[i][j], 0, 0, 0);
            }
        }
        __syncthreads();
    }

    #pragma unroll
    for (int i = 0; i < 4; ++i) {
        int rbase = row0 + wr * 64 + i * 16 + (lane >> 4) * 4;
        #pragma unroll
        for (int j = 0; j < 2; ++j) {
            int gc = col0 + wc * 32 + j * 16 + l15;
            float bc = b_leaf[gc];
            #pragma unroll
            for (int q = 0; q < 4; ++q)
                leaf_pre[(size_t)(rbase + q) * SZ + gc] =
                    fmaxf(acc[i][j][q] + bc, 0.f);
        }
    }
}

// leaf_norm: normalize rows, write chart_h + split Hcur + Sarr=0.
__global__ __launch_bounds__(256) void leaf_norm(
    const float* __restrict__ leaf_pre, float* __restrict__ chart_h,
    u16* __restrict__ Hc_hi, u16* __restrict__ Hc_lo,
    float* __restrict__ Sarr)
{
    const int r = blockIdx.x;               // 0..1535 = b*32+pos
    const int b = r >> 5, pos = r & 31;
    const int t = threadIdx.x, lane = t & 63, wave = t >> 6;
    __shared__ float red[4];

    float2 v = *(const float2*)&leaf_pre[(size_t)r * SZ + 2 * t];
    float sq = v.x * v.x + v.y * v.y;
    #pragma unroll
    for (int o = 32; o; o >>= 1) sq += __shfl_xor(sq, o);
    if (lane == 0) red[wave] = sq;
    __syncthreads();
    float nrm = sqrtf(red[0] + red[1] + red[2] + red[3]);
    float inv = 1.f / fmaxf(nrm, 1e-12f);
    v.x *= inv; v.y *= inv;
    *(float2*)&chart_h[((size_t)b * NCELLS + pos) * SZ + 2 * t] = v;
    u16 hx = f2bf(v.x), hy = f2bf(v.y);
    ((u32*)Hc_hi)[r * 256 + t] = pack2(hx, hy);
    ((u32*)Hc_lo)[r * 256 + t] = pack2(f2bf(v.x - bf2f(hx)), f2bf(v.y - bf2f(hy)));
    if (t == 0) Sarr[(size_t)b * NCELLS + pos] = 0.f;
}

// ---------------------------------------------------------------------------
// transform_mfma: ACU[cell][0:1536] = h[cell] @ Wcat from pre-split Hcur.
// 64x64 tile, 4 waves (2x2), wave 32x32, BK=32, ~20.5 KB LDS -> high
// occupancy; XCD-pinned col-tiles (each XCD owns 3 of 24 -> 393 KB W in L2).
// grid = 24 * nrt.
// ---------------------------------------------------------------------------
__global__ __launch_bounds__(256) void transform_mfma(
    const u16* __restrict__ Hc_hi, const u16* __restrict__ Hc_lo,
    const u16* __restrict__ WT_hi, const u16* __restrict__ WT_lo,
    float* __restrict__ ACU, int level, int nrt)
{
    __shared__ u16 Ah[64][40], Al[64][40];
    __shared__ u16 Bh[64][40], Bl[64][40];
    __shared__ int cidx[64];

    const int L = TT - level, rows = BB * L, off = off_of(level);
    // XCD pinning: id%8 = XCD x -> ct in [3x, 3x+3)
    const int id = blockIdx.x;
    const int w = (id & 7) * (3 * nrt) + (id >> 3);
    const int ct = w / nrt, rt = w % nrt;
    const int col0 = ct * 64;

    const int t = threadIdx.x;
    if (t < 64) {
        int g = rt * 64 + t;
        cidx[t] = (g < rows) ? ((g / L) * NCELLS + off + (g % L)) : -1;
    }

    // staging: thread -> (row/col = t>>2, k-chunk = (t&3)*8), one uint4 each
    const int srow = t >> 2, skc = (t & 3) * 8;
    const u16* aph = Hc_hi + (size_t)(rt * 64 + srow) * SZ + skc;
    const u16* apl = Hc_lo + (size_t)(rt * 64 + srow) * SZ + skc;
    const u16* bph = WT_hi + (size_t)(col0 + srow) * SZ + skc;
    const u16* bpl = WT_lo + (size_t)(col0 + srow) * SZ + skc;

    const int lane = t & 63, wv = t >> 6;
    const int wr = wv >> 1, wc = wv & 1;
    const int l15 = lane & 15, lko = (lane >> 4) * 8;

    f32x4 acc[2][2];
    #pragma unroll
    for (int i = 0; i < 2; ++i)
        #pragma unroll
        for (int j = 0; j < 2; ++j)
            #pragma unroll
            for (int e = 0; e < 4; ++e) acc[i][j][e] = 0.f;

    uint4 pah = *(const uint4*)aph;
    uint4 pal = *(const uint4*)apl;
    uint4 pbh = *(const uint4*)bph;
    uint4 pbl = *(const uint4*)bpl;

    for (int k0 = 0; k0 < SZ; k0 += 32) {
        *(uint4*)&Ah[srow][skc] = pah;
        *(uint4*)&Al[srow][skc] = pal;
        *(uint4*)&Bh[srow][skc] = pbh;
        *(uint4*)&Bl[srow][skc] = pbl;
        __syncthreads();

        if (k0 + 32 < SZ) {
            pah = *(const uint4*)(aph + k0 + 32);
            pal = *(const uint4*)(apl + k0 + 32);
            pbh = *(const uint4*)(bph + k0 + 32);
            pbl = *(const uint4*)(bpl + k0 + 32);
        }

        bf16x8 fah[2], fal[2], fbh[2], fbl[2];
        #pragma unroll
        for (int i = 0; i < 2; ++i) {
            fah[i] = *(const bf16x8*)&Ah[wr * 32 + i * 16 + l15][lko];
            fal[i] = *(const bf16x8*)&Al[wr * 32 + i * 16 + l15][lko];
        }
        #pragma unroll
        for (int j = 0; j < 2; ++j) {
            fbh[j] = *(const bf16x8*)&Bh[wc * 32 + j * 16 + l15][lko];
            fbl[j] = *(const bf16x8*)&Bl[wc * 32 + j * 16 + l15][lko];
        }
        #pragma unroll
        for (int i = 0; i < 2; ++i) {
            #pragma unroll
            for (int j = 0; j < 2; ++j) {
                acc[i][j] = __builtin_amdgcn_mfma_f32_16x16x32_bf16(
                    fah[i], fbh[j], acc[i][j], 0, 0, 0);
                acc[i][j] = __builtin_amdgcn_mfma_f32_16x16x32_bf16(
                    fah[i], fbl[j], acc[i][j], 0, 0, 0);
                acc[i][j] = __builtin_amdgcn_mfma_f32_16x16x32_bf16(
                    fal[i], fbh[j], acc[i][j], 0, 0, 0);
            }
        }
        __syncthreads();
    }

    #pragma unroll
    for (int i = 0; i < 2; ++i) {
        int rbase = wr * 32 + i * 16 + (lane >> 4) * 4;
        #pragma unroll
        for (int j = 0; j < 2; ++j) {
            int gc = col0 + wc * 32 + j * 16 + l15;
            #pragma unroll
            for (int q = 0; q < 4; ++q) {
                int ci = cidx[rbase + q];
                if (ci >= 0)
                    ACU[(size_t)ci * 1536 + gc] = acc[i][j][q];
            }
        }
    }
}

// ---------------------------------------------------------------------------
// Combine: one block per (b, pos). Writes chart_h + split Hcur + Sarr.
// ---------------------------------------------------------------------------
__global__ __launch_bounds__(256) void combine_kernel(
    float* __restrict__ chart_h, const float* __restrict__ ACU,
    float* __restrict__ Sarr, const float* __restrict__ b_comp,
    u16* __restrict__ Hc_hi, u16* __restrict__ Hc_lo, int level)
{
    const int L = TT - level, N = level;
    const int b = blockIdx.x / L, pos = blockIdx.x % L;
    const int off = off_of(level);

    __shared__ float s_lds[32], p_lds[32];
    __shared__ int lcell[32], rcell[32];
    __shared__ float hred[4][512];
    __shared__ float red[4];

    const int t = threadIdx.x, lane = t & 63, wv = t >> 6;

    if (t < N) {
        lcell[t] = b * NCELLS + off_of(t) + pos;
        rcell[t] = b * NCELLS + off_of(level - t - 1) + pos + t + 1;
    }
    __syncthreads();

    // phase 1: s_n = u_l . h_r + s_l + s_r
    for (int n = wv; n < N; n += 4) {
        const float* u  = ACU + (size_t)lcell[n] * 1536 + 1024;
        const float* hr = chart_h + (size_t)rcell[n] * SZ;
        float d0 = 0.f, d1 = 0.f, d2 = 0.f, d3 = 0.f;
        int j = lane * 2;
        {
            float2 uv = *(const float2*)&u[j];
            float2 hv = *(const float2*)&hr[j];
            d0 = fmaf(uv.x, hv.x, fmaf(uv.y, hv.y, d0));
        }
        {
            float2 uv = *(const float2*)&u[j + 128];
            float2 hv = *(const float2*)&hr[j + 128];
            d1 = fmaf(uv.x, hv.x, fmaf(uv.y, hv.y, d1));
        }
        {
            float2 uv = *(const float2*)&u[j + 256];
            float2 hv = *(const float2*)&hr[j + 256];
            d2 = fmaf(uv.x, hv.x, fmaf(uv.y, hv.y, d2));
        }
        {
            float2 uv = *(const float2*)&u[j + 384];
            float2 hv = *(const float2*)&hr[j + 384];
            d3 = fmaf(uv.x, hv.x, fmaf(uv.y, hv.y, d3));
        }
        float d = (d0 + d1) + (d2 + d3);
        #pragma unroll
        for (int o = 32; o; o >>= 1) d += __shfl_xor(d, o);
        if (lane == 0)
            s_lds[n] = d + Sarr[lcell[n]] + Sarr[rcell[n]];
    }
    __syncthreads();

    // phase 1b: softmax + sbar (wave 0)
    if (wv == 0) {
        float sv = (lane < N) ? s_lds[lane] : -INFINITY;
        float m = sv;
        #pragma unroll
        for (int o = 32; o; o >>= 1) m = fmaxf(m, __shfl_xor(m, o));
        float e = (lane < N) ? expf(sv - m) : 0.f;
        float sum = e;
        #pragma unroll
        for (int o = 32; o; o >>= 1) sum += __shfl_xor(sum, o);
        float p = e / sum;
        if (lane < N) p_lds[lane] = p;
        float sb = (lane < N) ? sv * p : 0.f;
        #pragma unroll
        for (int o = 32; o; o >>= 1) sb += __shfl_xor(sb, o);
        if (lane == 0) Sarr[(size_t)b * NCELLS + off + pos] = sb;
    }
    __syncthreads();

    // phase 2: per-wave partial hbar
    float ax[4], ay[4];
    float2 bc[4];
    #pragma unroll
    for (int q = 0; q < 4; ++q) {
        ax[q] = 0.f; ay[q] = 0.f;
        bc[q] = *(const float2*)&b_comp[lane * 2 + q * 128];
    }
    for (int n = wv; n < N; n += 4) {
        const float* A_ = ACU + (size_t)lcell[n] * 1536;
        const float* C_ = ACU + (size_t)rcell[n] * 1536 + 512;
        float p = p_lds[n];
        #pragma unroll
        for (int q = 0; q < 4; ++q) {
            int j = lane * 2 + q * 128;
            float2 va = *(const float2*)&A_[j];
            float2 vc = *(const float2*)&C_[j];
            ax[q] = fmaf(p, fmaxf(va.x + vc.x + bc[q].x, 0.f), ax[q]);
            ay[q] = fmaf(p, fmaxf(va.y + vc.y + bc[q].y, 0.f), ay[q]);
        }
    }
    #pragma unroll
    for (int q = 0; q < 4; ++q)
        *(float2*)&hred[wv][lane * 2 + q * 128] = make_float2(ax[q], ay[q]);
    __syncthreads();

    float hx = hred[0][2 * t] + hred[1][2 * t] + hred[2][2 * t] + hred[3][2 * t];
    float hy = hred[0][2 * t + 1] + hred[1][2 * t + 1]
             + hred[2][2 * t + 1] + hred[3][2 * t + 1];

    float sq = hx * hx + hy * hy;
    #pragma unroll
    for (int o = 32; o; o >>= 1) sq += __shfl_xor(sq, o);
    if (lane == 0) red[wv] = sq;
    __syncthreads();
    float nrm = sqrtf(red[0] + red[1] + red[2] + red[3]);
    float inv = 1.f / fmaxf(nrm, 1e-12f);
    hx *= inv; hy *= inv;
    size_t obase = ((size_t)b * NCELLS + off + pos) * SZ;
    *(float2*)&chart_h[obase + 2 * t] = make_float2(hx, hy);
    int g = b * L + pos;
    u16 hhx = f2bf(hx), hhy = f2bf(hy);
    ((u32*)Hc_hi)[g * 256 + t] = pack2(hhx, hhy);
    ((u32*)Hc_lo)[g * 256 + t] = pack2(f2bf(hx - bf2f(hhx)), f2bf(hy - bf2f(hhy)));
}

// ---------------------------------------------------------------------------
extern "C" void kernel_launch(void* const* d_in, const int* in_sizes, int n_in,
                              void* d_out, int out_size, void* d_ws, size_t ws_size,
                              hipStream_t stream)
{
    const float* x      = (const float*)d_in[0];
    const float* w_leaf = (const float*)d_in[1];
    const float* b_leaf = (const float*)d_in[2];
    const float* w_comp = (const float*)d_in[3];
    const float* b_comp = (const float*)d_in[4];
    const float* s_bil  = (const float*)d_in[5];
    float* chart_h = (float*)d_out;

    char* ws = (char*)d_ws;
    float* ACU  = (float*)ws;                      ws += (size_t)BB * NCELLS * 1536 * 4;
    float* Sarr = (float*)ws;                      ws += (size_t)BB * NCELLS * 4;
    u16* WT_hi  = (u16*)ws;                        ws += (size_t)1536 * SZ * 2;
    u16* WT_lo  = (u16*)ws;                        ws += (size_t)1536 * SZ * 2;
    u16* WLT_hi = (u16*)ws;                        ws += (size_t)SZ * DD * 2;
    u16* WLT_lo = (u16*)ws;                        ws += (size_t)SZ * DD * 2;
    u16* Hc_hi  = (u16*)ws;                        ws += (size_t)BB * TT * SZ * 2;
    u16* Hc_lo  = (u16*)ws;                        ws += (size_t)BB * TT * SZ * 2;
    float* leaf_pre = (float*)ws;                  ws += (size_t)BB * TT * SZ * 4;

    prep_w<<<(1536 * SZ) / 256, 256, 0, stream>>>(w_comp, s_bil, WT_hi, WT_lo);
    prep_wl<<<(SZ * DD) / 256, 256, 0, stream>>>(w_leaf, WLT_hi, WLT_lo);
    leaf_mfma<<<dim3(8, 12), 256, 0, stream>>>(x, WLT_hi, WLT_lo, b_leaf, leaf_pre);
    leaf_norm<<<BB * TT, 256, 0, stream>>>(leaf_pre, chart_h, Hc_hi, Hc_lo, Sarr);

    {
        int nrt = (BB * TT + 63) / 64;   // 24
        transform_mfma<<<24 * nrt, 256, 0, stream>>>(
            Hc_hi, Hc_lo, WT_hi, WT_lo, ACU, 0, nrt);
    }

    for (int level = 1; level < TT; ++level) {
        int L = TT - level;
        combine_kernel<<<BB * L, 256, 0, stream>>>(
            chart_h, ACU, Sarr, b_comp, Hc_hi, Hc_lo, level);
        if (level < TT - 1) {
            int nrt = (BB * L + 63) / 64;
            transform_mfma<<<24 * nrt, 256, 0, stream>>>(
                Hc_hi, Hc_lo, WT_hi, WT_lo, ACU, level, nrt);
        }
    }
}